// Round 11
// baseline (191.959 us; speedup 1.0000x reference)
//
#include <hip/hip_runtime.h>
#include <stdint.h>

#define GMAX 128
#define TK 128            // FG_ROIS_PER_IMAGE = BG_ROIS_PER_IMAGE = 128
#define NBINS 4096
#define CLDS 2048         // per-mask LDS candidate cap (real cnt ~150-300)
#define NUM_CLASSES 21

typedef float f32x4u __attribute__((ext_vector_type(4), aligned(4)));

// ---------------------------------------------------------------------------
// JAX threefry2x32 block cipher (key = [hi32(seed), lo32(seed)] = [0, 42])
// ---------------------------------------------------------------------------
__device__ __forceinline__ void threefry2x32(uint32_t k0, uint32_t k1,
                                             uint32_t& x0, uint32_t& x1) {
  uint32_t ks0 = k0, ks1 = k1, ks2 = k0 ^ k1 ^ 0x1BD11BDAu;
  x0 += ks0; x1 += ks1;
#define TF_ROUND(r) { x0 += x1; x1 = (x1 << (r)) | (x1 >> (32 - (r))); x1 ^= x0; }
  TF_ROUND(13) TF_ROUND(15) TF_ROUND(26) TF_ROUND(6)
  x0 += ks1; x1 += ks2 + 1u;
  TF_ROUND(17) TF_ROUND(29) TF_ROUND(16) TF_ROUND(24)
  x0 += ks2; x1 += ks0 + 2u;
  TF_ROUND(13) TF_ROUND(15) TF_ROUND(26) TF_ROUND(6)
  x0 += ks0; x1 += ks1 + 3u;
  TF_ROUND(17) TF_ROUND(29) TF_ROUND(16) TF_ROUND(24)
  x0 += ks1; x1 += ks2 + 4u;
  TF_ROUND(13) TF_ROUND(15) TF_ROUND(26) TF_ROUND(6)
  x0 += ks2; x1 += ks0 + 5u;
#undef TF_ROUND
}

// ---------------------------------------------------------------------------
// FUSED kernel (r15): score (r12-verbatim) + last-block tail doing
// threshold -> compact -> finalize. Launch chain = memset + THIS (2 enqueues
// vs r12's 4). No cooperative launch, no device queries (r13 lesson).
//
// Phase 1 (all blocks, r12-verified @109.9us total): 512 threads = 8 waves
//   cover 256 ROIs; waves 0-3 scan g in [0,64), waves 4-7 scan [64,128) for
//   the SAME ROIs. half is wave-uniform (readfirstlane) -> gt4[g0+g] is an
//   s_load on the scalar pipe; ga staged once in LDS (bit-identical FP
//   sequence), read at a wave-uniform address (pure broadcast). Cross-half
//   combine via sortable key (bits(best)<<32)|(127-bi): max == (max ov,
//   tie -> min g) == jnp.argmax first-max. Lower 256 threads do threefry +
//   coalesced score write + hist atomics (device-scope).
//
// Done-counter handoff (verified r7-r12): release = s_waitcnt vmcnt(0) +
//   __syncthreads (atomics AND plain stores are at the L2 coherence point;
//   CDNA L1 is write-through). NO __threadfence (r6: buffer_wbl2 ~50us).
//   Last block's reads of hist (agent atomic loads) and score (plain loads,
//   lines provably cold in this block's L1 — it only ever WROTE its own
//   slice) are the exact patterns r10/r11's fused tail ran successfully.
//
// Tail (last block only, ~13us serial):
//   Phase 2: exact per-mask threshold bin (r12-verbatim scan) -> LDS s_bth.
//   Phase 3: one pass over score[] (uint4), filter by s_bth, append keys
//            ((ubits+1)<<32)|~i to per-mask LDS cand via LDS atomics.
//   Phase 4: rank-based top-TK (keys unique -> rank = #{keys > mine} == XLA
//            stable top_k order, append-order independent; verified r6-r12)
//            + <TK pad (lowest-index non-masked) + bbox transform + output.
// Output layout: rois[256*5] | labels[256] | targets[256*84]
// meta: [2]=done_counter only.
// ---------------------------------------------------------------------------
__global__ void __launch_bounds__(512)
fused_kernel(const float* __restrict__ all_rois,   // [N,5]
             const float* __restrict__ gt_boxes,   // [G,4]
             const int* __restrict__ gt_labels,
             uint32_t* __restrict__ score,         // [M]
             uint32_t* __restrict__ hist,          // [2*NBINS] fg|bg
             int* __restrict__ meta,
             float* __restrict__ out,
             int N, int M) {
  // LDS union: [0,32768) = phase1 lds_key/sga | phase2 gs | phase3/4 cand
  __shared__ __align__(16) char smem[39488];
  uint64_t* lds_key = (uint64_t*)smem;              // [256]  (phase 1)
  float*    sga     = (float*)(smem + 2048);        // [128]  (phase 1)
  uint64_t* gs      = (uint64_t*)smem;              // [512]  (phase 2)
  uint64_t* cand    = (uint64_t*)smem;              // [2][CLDS] (phase 3/4)
  int*      s_jstar = (int*)(smem + 32768);
  int*      s_bth   = (int*)(smem + 32776);
  int*      s_cnt   = (int*)(smem + 32784);
  unsigned* s_prevp = (unsigned*)(smem + 32792);
  int*      keep    = (int*)(smem + 32800);         // [256]
  int*      fgvalid = (int*)(smem + 33824);         // [128]
  int*      s_label = (int*)(smem + 34336);         // [256]
  float*    s_tx    = (float*)(smem + 35360);
  float*    s_ty    = (float*)(smem + 36384);
  float*    s_tw    = (float*)(smem + 37408);
  float*    s_th    = (float*)(smem + 38432);

  const int t = threadIdx.x;
  const int lane = t & 63;
  const int wave = t >> 6;                               // 0..7
  const int wq = wave & 3;                               // ROI group 0..3
  const int half = __builtin_amdgcn_readfirstlane(wave >> 2);  // 0/1, SGPR
  const int i = blockIdx.x * 256 + wq * 64 + lane;       // ROI index
  const bool active = (i < M);

  // ======== phase 1: score (r12-verbatim) ========
  const float4* __restrict__ gt4 = reinterpret_cast<const float4*>(gt_boxes);
  if (t < GMAX) {
    float4 b = gt4[t];
    sga[t] = __fmul_rn(__fadd_rn(__fsub_rn(b.z, b.x), 1.0f),
                       __fadd_rn(__fsub_rn(b.w, b.y), 1.0f));
  }
  float bx1 = 0.0f, by1 = 0.0f, bx2 = 0.0f, by2 = 0.0f;
  if (active) {
    if (i < N) {
      f32x4u v = *reinterpret_cast<const f32x4u*>(all_rois + (size_t)i * 5 + 1);
      bx1 = v.x; by1 = v.y; bx2 = v.z; by2 = v.w;
    } else {
      float4 b = gt4[i - N];
      bx1 = b.x; by1 = b.y; bx2 = b.z; by2 = b.w;
    }
  }
  const float area = __fmul_rn(__fadd_rn(__fsub_rn(bx2, bx1), 1.0f),
                               __fadd_rn(__fsub_rn(by2, by1), 1.0f));
  __syncthreads();                     // sga ready

  float best = -1.0f;
  int bi = 0;
  const int g0 = half * 64;
#pragma unroll 8
  for (int g = 0; g < 64; ++g) {
    const float4 gb = gt4[g0 + g];     // SGPR base + const -> s_load_dwordx4
    const float ga = sga[g0 + g];      // wave-uniform -> LDS broadcast
    float ix1 = fmaxf(bx1, gb.x);
    float iy1 = fmaxf(by1, gb.y);
    float ix2 = fminf(bx2, gb.z);
    float iy2 = fminf(by2, gb.w);
    float iw = fmaxf(__fadd_rn(__fsub_rn(ix2, ix1), 1.0f), 0.0f);
    float ih = fmaxf(__fadd_rn(__fsub_rn(iy2, iy1), 1.0f), 0.0f);
    float inter = __fmul_rn(iw, ih);
    float uni = __fsub_rn(__fadd_rn(area, ga), inter);
    float ov = __fdiv_rn(inter, uni);  // IEEE-rounded, matches XLA
    if (ov > best) { best = ov; bi = g0 + g; }  // first-max within half
  }

  const uint64_t mykey = ((uint64_t)__float_as_uint(best) << 32) |
                         (uint64_t)(uint32_t)(127 - bi);
  if (half == 1) lds_key[wq * 64 + lane] = mykey;
  __syncthreads();

  if (half == 0) {
    uint64_t kk = lds_key[wq * 64 + lane];
    if (mykey > kk) kk = mykey;
    best = __uint_as_float((uint32_t)(kk >> 32));
    bi = 127 - (int)(kk & 127ull);
    if (active) {
      uint32_t cx0 = 0u, cx1 = (uint32_t)i;
      threefry2x32(0u, 42u, cx0, cx1);
      uint32_t ubits = (cx0 ^ cx1) >> 9;       // mantissa of u in [0,1)
      uint32_t fg = (best >= 0.5f) ? 1u : 0u;
      uint32_t bg = (!fg && best >= 0.1f) ? 1u : 0u;
      score[i] = (ubits << 9) | ((uint32_t)bi << 2) | (fg << 1) | bg;
      if (fg)      atomicAdd(&hist[ubits >> 11], 1u);
      else if (bg) atomicAdd(&hist[NBINS + (ubits >> 11)], 1u);
    }
  }

  // ======== done-counter handoff (verified release) ========
  asm volatile("s_waitcnt vmcnt(0)" ::: "memory");
  __syncthreads();
  if (t == 0)
    *s_prevp = atomicAdd((unsigned int*)&meta[2], 1u);
  __syncthreads();
  if (*s_prevp != gridDim.x - 1) return;
  __syncthreads();                     // lds_key/sga dead; gs region reusable

  // ======== phase 2: exact per-mask threshold bins (r12-verbatim) ========
  {
    const int b0 = 8 * t;              // 8 bins/thread, 512*8 = 4096
    uint64_t acc = 0;
    for (int k = 0; k < 8; ++k) {
      uint32_t hf = __hip_atomic_load(&hist[b0 + k], __ATOMIC_RELAXED,
                                      __HIP_MEMORY_SCOPE_AGENT);
      uint32_t hb = __hip_atomic_load(&hist[NBINS + b0 + k], __ATOMIC_RELAXED,
                                      __HIP_MEMORY_SCOPE_AGENT);
      acc += ((uint64_t)hf << 32) | (uint64_t)hb;
    }
    gs[t] = acc;
    if (t < 2) s_jstar[t] = -1;
    __syncthreads();
    for (int d = 1; d < 512; d <<= 1) {   // inclusive suffix scan
      uint64_t add = (t + d < 512) ? gs[t + d] : 0ull;
      __syncthreads();
      gs[t] += add;
      __syncthreads();
    }
    uint32_t vfg = (uint32_t)(gs[t] >> 32);
    uint32_t vbg = (uint32_t)gs[t];
    uint32_t nfg = (t < 511) ? (uint32_t)(gs[t + 1] >> 32) : 0u;
    uint32_t nbg = (t < 511) ? (uint32_t)gs[t + 1] : 0u;
    if (vfg >= (uint32_t)TK && (t == 511 || nfg < (uint32_t)TK)) s_jstar[0] = t;
    if (vbg >= (uint32_t)TK && (t == 511 || nbg < (uint32_t)TK)) s_jstar[1] = t;
    __syncthreads();
    if (t == 0) {
      for (int m = 0; m < 2; ++m) {
        int j = s_jstar[m], B = -1;
        if (j >= 0) {
          uint32_t base = 0;
          if (j < 511)
            base = (m == 0) ? (uint32_t)(gs[j + 1] >> 32) : (uint32_t)gs[j + 1];
          B = 8 * j;
          for (int b = 8 * j + 7; b >= 8 * j; --b) {
            base += __hip_atomic_load(&hist[m * NBINS + b], __ATOMIC_RELAXED,
                                      __HIP_MEMORY_SCOPE_AGENT);
            if (base >= (uint32_t)TK) { B = b; break; }
          }
        }
        s_bth[m] = B;
      }
    }
    if (t < 2) s_cnt[t] = 0;
    __syncthreads();                   // s_bth/s_cnt ready; gs dead
  }

  // ======== phase 3: compact into LDS (one pass over score) ========
  {
    const int bth0 = s_bth[0], bth1 = s_bth[1];
    for (int base = t * 4; base < M; base += 512 * 4) {
      uint32_t ss[4];
      int lim;
      if (base + 3 < M) {
        uint4 s4 = *reinterpret_cast<const uint4*>(score + base);
        ss[0] = s4.x; ss[1] = s4.y; ss[2] = s4.z; ss[3] = s4.w;
        lim = 4;
      } else {
        lim = M - base;
        for (int k = 0; k < lim; ++k) ss[k] = score[base + k];
      }
      for (int k = 0; k < lim; ++k) {
        uint32_t s = ss[k];
        uint32_t mb = s & 3u;
        if (!mb) continue;
        int m = (mb & 2u) ? 0 : 1;
        int B = (m == 0) ? bth0 : bth1;
        if (B >= 0 && (int)(s >> 20) < B) continue;
        int p = atomicAdd(&s_cnt[m], 1);
        if (p < CLDS)
          cand[m * CLDS + p] = (((uint64_t)((s >> 9) + 1u)) << 32) |
                               (uint64_t)(~(uint32_t)(base + k));
      }
    }
    __syncthreads();
  }

  // ======== phase 4: rank-based top-TK + finalize ========
  for (int m = 0; m < 2; ++m) {
    int cnt = s_cnt[m]; if (cnt > CLDS) cnt = CLDS;
    for (int p = t; p < cnt; p += 512) {
      uint64_t key = cand[m * CLDS + p];
      int r = 0;
      for (int j = 0; j < cnt; ++j) r += (cand[m * CLDS + j] > key) ? 1 : 0;
      if (r < TK) {
        keep[m * TK + r] = (int)(~(uint32_t)(key & 0xFFFFFFFFull));
        if (m == 0) fgvalid[r] = 1;
      }
    }
    __syncthreads();
    if (cnt < TK && t == 0) {         // pad with lowest-index non-masked
      int fill = cnt;                 // (JAX -1.0 tie semantics)
      uint32_t mask_bit = (m == 0) ? 2u : 1u;
      for (int i2 = 0; i2 < M && fill < TK; ++i2)
        if (!(score[i2] & mask_bit)) {
          keep[m * TK + fill] = i2;
          if (m == 0) fgvalid[fill] = 0;
          fill++;
        }
    }
    __syncthreads();
  }

  const int R = 2 * TK;
  float* rois_out   = out;
  float* labels_out = out + (size_t)R * 5;
  float* bt_out     = out + (size_t)R * 5 + R;

  if (t < R) {
    const int ii = keep[t];
    float rimg, rx1, ry1, rx2, ry2;
    if (ii < N) {
      rimg = all_rois[(size_t)ii * 5 + 0];
      rx1  = all_rois[(size_t)ii * 5 + 1];
      ry1  = all_rois[(size_t)ii * 5 + 2];
      rx2  = all_rois[(size_t)ii * 5 + 3];
      ry2  = all_rois[(size_t)ii * 5 + 4];
    } else {
      int g = ii - N;
      rimg = 0.0f;
      rx1 = gt_boxes[g * 4 + 0]; ry1 = gt_boxes[g * 4 + 1];
      rx2 = gt_boxes[g * 4 + 2]; ry2 = gt_boxes[g * 4 + 3];
    }
    rois_out[t * 5 + 0] = rimg;
    rois_out[t * 5 + 1] = rx1;
    rois_out[t * 5 + 2] = ry1;
    rois_out[t * 5 + 3] = rx2;
    rois_out[t * 5 + 4] = ry2;

    const int ga2 = (int)((score[ii] >> 2) & 127u);
    int label = (t < TK && fgvalid[t]) ? gt_labels[ga2] : 0;
    labels_out[t] = (float)label;
    s_label[t] = label;

    float gx1 = gt_boxes[ga2 * 4 + 0], gy1 = gt_boxes[ga2 * 4 + 1];
    float gx2 = gt_boxes[ga2 * 4 + 2], gy2 = gt_boxes[ga2 * 4 + 3];
    float ew = rx2 - rx1 + 1.0f, eh = ry2 - ry1 + 1.0f;
    float ecx = rx1 + 0.5f * ew, ecy = ry1 + 0.5f * eh;
    float gw = gx2 - gx1 + 1.0f, gh = gy2 - gy1 + 1.0f;
    float gcx = gx1 + 0.5f * gw, gcy = gy1 + 0.5f * gh;
    s_tx[t] = (gcx - ecx) / ew;
    s_ty[t] = (gcy - ecy) / eh;
    s_tw[t] = logf(gw / ew);
    s_th[t] = logf(gh / eh);
  }
  __syncthreads();

  const int TOT = R * 4 * NUM_CLASSES;
  for (int idx = t; idx < TOT; idx += 512) {
    int r = idx / (4 * NUM_CLASSES);
    int c = idx - r * (4 * NUM_CLASSES);
    int lab = s_label[r];
    float v = 0.0f;
    if (lab > 0 && (c >> 2) == lab) {
      int cc = c & 3;
      v = (cc == 0) ? s_tx[r] : (cc == 1) ? s_ty[r]
                              : (cc == 2) ? s_tw[r] : s_th[r];
    }
    bt_out[idx] = v;
  }
}

// ---------------------------------------------------------------------------
extern "C" void kernel_launch(void* const* d_in, const int* in_sizes, int n_in,
                              void* d_out, int out_size, void* d_ws, size_t ws_size,
                              hipStream_t stream) {
  const float* all_rois = (const float*)d_in[0];
  const float* gt_boxes = (const float*)d_in[1];
  const int*   gt_labels = (const int*)d_in[2];
  const int N = in_sizes[0] / 5;
  const int G = in_sizes[2];
  const int M = N + G;
  (void)G;

  // workspace: [meta 256B][hist 32KB][score M*4]
  char* ws = (char*)d_ws;
  int* meta = (int*)ws;
  uint32_t* hist = (uint32_t*)(ws + 256);
  uint32_t* score = (uint32_t*)(ws + 256 + (size_t)2 * NBINS * 4);
  float* out = (float*)d_out;

  hipMemsetAsync(ws, 0, 256 + (size_t)2 * NBINS * 4, stream);
  const int nblocks = (M + 255) / 256;        // 256 ROIs per 512-thread block
  fused_kernel<<<nblocks, 512, 0, stream>>>(all_rois, gt_boxes, gt_labels,
                                            score, hist, meta, out, N, M);
}

// Round 12
// 107.180 us; speedup vs baseline: 1.7910x; 1.7910x over previous
//
#include <hip/hip_runtime.h>
#include <stdint.h>

#define GMAX 128
#define TK 128            // FG_ROIS_PER_IMAGE = BG_ROIS_PER_IMAGE = 128
#define NBINS 4096
#define CAND_MAX 4096
#define NUM_CLASSES 21

typedef float f32x4u __attribute__((ext_vector_type(4), aligned(4)));

// ---------------------------------------------------------------------------
// JAX threefry2x32 block cipher (key = [hi32(seed), lo32(seed)] = [0, 42])
// ---------------------------------------------------------------------------
__device__ __forceinline__ void threefry2x32(uint32_t k0, uint32_t k1,
                                             uint32_t& x0, uint32_t& x1) {
  uint32_t ks0 = k0, ks1 = k1, ks2 = k0 ^ k1 ^ 0x1BD11BDAu;
  x0 += ks0; x1 += ks1;
#define TF_ROUND(r) { x0 += x1; x1 = (x1 << (r)) | (x1 >> (32 - (r))); x1 ^= x0; }
  TF_ROUND(13) TF_ROUND(15) TF_ROUND(26) TF_ROUND(6)
  x0 += ks1; x1 += ks2 + 1u;
  TF_ROUND(17) TF_ROUND(29) TF_ROUND(16) TF_ROUND(24)
  x0 += ks2; x1 += ks0 + 2u;
  TF_ROUND(13) TF_ROUND(15) TF_ROUND(26) TF_ROUND(6)
  x0 += ks0; x1 += ks1 + 3u;
  TF_ROUND(17) TF_ROUND(29) TF_ROUND(16) TF_ROUND(24)
  x0 += ks1; x1 += ks2 + 4u;
  TF_ROUND(13) TF_ROUND(15) TF_ROUND(26) TF_ROUND(6)
  x0 += ks2; x1 += ks0 + 5u;
#undef TF_ROUND
}

// ---------------------------------------------------------------------------
// Kernel 1 (r16): 4-WAY WAVE-SPLIT at 1024 threads/block. 16 waves cover 256
// ROIs: wave = (quarter q)*4 + (ROI group wq); wave wq+4*q scans g in
// [32q, 32q+32) for ROI group wq (64 ROIs). q is wave-uniform
// (readfirstlane) -> gt4[g0+g] stays an s_load on the scalar pipe (r8/r12's
// proven VALU-dense body); ga from LDS broadcast (bit-identical staging,
// r12-verified). Wave supply 2x r12 (15.3/SIMD demanded -> saturates the
// 8/SIMD cap at 2 blocks/CU) at identical total VALU work and identical
// 978-block epilogue amortization (r10's 4-way failure was its 64-ROI
// blocks, not the split arity). Cross-quarter combine via the r10-verified
// sortable key (bits(best)<<32)|(127-bi): max == (max ov, tie -> min g) ==
// jnp.argmax first-max. Quarter-0 waves finalize (threefry + coalesced
// score write + hist atomics; same totals). Last block (done-counter on
// meta[2]) computes exact per-mask threshold bins (1024 thr, 4 bins each);
// release = s_waitcnt vmcnt(0) + barrier (hist written only by device-scope
// atomics — verified r7-r12). NO __threadfence (r6: buffer_wbl2 ~50us).
// meta layout: [0]=cnt_fg [1]=cnt_bg [2]=done_score [4]=bth_fg [5]=bth_bg
// ---------------------------------------------------------------------------
__global__ void __launch_bounds__(1024)
score_kernel(const float* __restrict__ all_rois,   // [N,5]
             const float* __restrict__ gt_boxes,   // [G,4]
             uint32_t* __restrict__ score,         // [M]
             uint32_t* __restrict__ hist,          // [2*NBINS] fg|bg
             int* __restrict__ meta,
             int N, int M, int G) {
  __shared__ uint64_t lds_key[768];    // quarters 1..3 publish here
  __shared__ float sga[GMAX];
  const int t = threadIdx.x;
  const int lane = t & 63;
  const int wave = t >> 6;                               // 0..15
  const int wq = wave & 3;                               // ROI group 0..3
  const int q = __builtin_amdgcn_readfirstlane(wave >> 2);  // quarter, SGPR
  const int i = blockIdx.x * 256 + wq * 64 + lane;       // ROI index
  const bool active = (i < M);

  const float4* __restrict__ gt4 = reinterpret_cast<const float4*>(gt_boxes);
  if (t < GMAX) {
    float4 b = gt4[t];
    sga[t] = __fmul_rn(__fadd_rn(__fsub_rn(b.z, b.x), 1.0f),
                       __fadd_rn(__fsub_rn(b.w, b.y), 1.0f));
  }

  float bx1 = 0.0f, by1 = 0.0f, bx2 = 0.0f, by2 = 0.0f;
  if (active) {
    if (i < N) {
      f32x4u v = *reinterpret_cast<const f32x4u*>(all_rois + (size_t)i * 5 + 1);
      bx1 = v.x; by1 = v.y; bx2 = v.z; by2 = v.w;
    } else {
      float4 b = gt4[i - N];
      bx1 = b.x; by1 = b.y; bx2 = b.z; by2 = b.w;
    }
  }
  const float area = __fmul_rn(__fadd_rn(__fsub_rn(bx2, bx1), 1.0f),
                               __fadd_rn(__fsub_rn(by2, by1), 1.0f));
  __syncthreads();                     // sga ready

  float best = -1.0f;
  int bi = 0;
  const int g0 = q * 32;
#pragma unroll 8
  for (int g = 0; g < 32; ++g) {
    const float4 gb = gt4[g0 + g];     // SGPR base + const -> s_load_dwordx4
    const float ga = sga[g0 + g];      // wave-uniform -> LDS broadcast
    float ix1 = fmaxf(bx1, gb.x);
    float iy1 = fmaxf(by1, gb.y);
    float ix2 = fminf(bx2, gb.z);
    float iy2 = fminf(by2, gb.w);
    float iw = fmaxf(__fadd_rn(__fsub_rn(ix2, ix1), 1.0f), 0.0f);
    float ih = fmaxf(__fadd_rn(__fsub_rn(iy2, iy1), 1.0f), 0.0f);
    float inter = __fmul_rn(iw, ih);
    float uni = __fsub_rn(__fadd_rn(area, ga), inter);
    float ov = __fdiv_rn(inter, uni);  // IEEE-rounded, matches XLA
    if (ov > best) { best = ov; bi = g0 + g; }  // first-max within quarter
  }

  // sortable key: best in [0,1] after the loop -> bits order-isomorphic;
  // tie (equal best) -> larger (127-bi) -> smaller bi == first-max.
  const uint64_t mykey = ((uint64_t)__float_as_uint(best) << 32) |
                         (uint64_t)(uint32_t)(127 - bi);
  if (q != 0) lds_key[(q - 1) * 256 + wq * 64 + lane] = mykey;
  __syncthreads();

  if (q == 0) {
    const int o = wq * 64 + lane;
    uint64_t k1 = lds_key[o];
    uint64_t k2 = lds_key[256 + o];
    uint64_t k3 = lds_key[512 + o];
    uint64_t kk = (k1 > mykey) ? k1 : mykey;
    kk = (k2 > kk) ? k2 : kk;
    kk = (k3 > kk) ? k3 : kk;
    best = __uint_as_float((uint32_t)(kk >> 32));
    bi = 127 - (int)(kk & 127ull);

    if (active) {
      // partitionable threefry: counter (hi=0, lo=i), output = x0 ^ x1
      uint32_t cx0 = 0u, cx1 = (uint32_t)i;
      threefry2x32(0u, 42u, cx0, cx1);
      uint32_t ubits = (cx0 ^ cx1) >> 9;       // mantissa of u in [0,1)
      uint32_t fg = (best >= 0.5f) ? 1u : 0u;
      uint32_t bg = (!fg && best >= 0.1f) ? 1u : 0u;
      score[i] = (ubits << 9) | ((uint32_t)bi << 2) | (fg << 1) | bg;
      if (fg)      atomicAdd(&hist[ubits >> 11], 1u);
      else if (bg) atomicAdd(&hist[NBINS + (ubits >> 11)], 1u);
    }
  }

  // ---- last-block exact threshold computation ----
  // Release: this wave's hist atomics retired at the coherence point ...
  asm volatile("s_waitcnt vmcnt(0)" ::: "memory");
  __syncthreads();                    // ... and every wave in this block too.
  __shared__ unsigned s_prev;
  if (t == 0) s_prev = atomicAdd((unsigned int*)&meta[2], 1u);
  __syncthreads();
  if (s_prev != gridDim.x - 1) return;

  __shared__ uint64_t gs[1024];
  __shared__ int s_jstar[2];
  const int b0 = 4 * t;               // 4 bins per thread, 1024*4 = 4096
  uint64_t acc = 0;
  for (int k = 0; k < 4; ++k) {
    uint32_t hf = __hip_atomic_load(&hist[b0 + k], __ATOMIC_RELAXED,
                                    __HIP_MEMORY_SCOPE_AGENT);
    uint32_t hb = __hip_atomic_load(&hist[NBINS + b0 + k], __ATOMIC_RELAXED,
                                    __HIP_MEMORY_SCOPE_AGENT);
    acc += ((uint64_t)hf << 32) | (uint64_t)hb;
  }
  gs[t] = acc;
  if (t < 2) s_jstar[t] = -1;
  __syncthreads();
  for (int d = 1; d < 1024; d <<= 1) { // inclusive suffix scan
    uint64_t add = (t + d < 1024) ? gs[t + d] : 0ull;
    __syncthreads();
    gs[t] += add;
    __syncthreads();
  }
  uint32_t vfg = (uint32_t)(gs[t] >> 32);
  uint32_t vbg = (uint32_t)gs[t];
  uint32_t nfg = (t < 1023) ? (uint32_t)(gs[t + 1] >> 32) : 0u;
  uint32_t nbg = (t < 1023) ? (uint32_t)gs[t + 1] : 0u;
  if (vfg >= (uint32_t)TK && (t == 1023 || nfg < (uint32_t)TK)) s_jstar[0] = t;
  if (vbg >= (uint32_t)TK && (t == 1023 || nbg < (uint32_t)TK)) s_jstar[1] = t;
  __syncthreads();
  if (t == 0) {
    for (int m = 0; m < 2; ++m) {
      int j = s_jstar[m], B = -1;
      if (j >= 0) {
        uint32_t base = 0;
        if (j < 1023)
          base = (m == 0) ? (uint32_t)(gs[j + 1] >> 32) : (uint32_t)gs[j + 1];
        B = 4 * j;
        for (int b = 4 * j + 3; b >= 4 * j; --b) {
          base += __hip_atomic_load(&hist[m * NBINS + b], __ATOMIC_RELAXED,
                                    __HIP_MEMORY_SCOPE_AGENT);
          if (base >= (uint32_t)TK) { B = b; break; }
        }
      }
      meta[4 + m] = B;
    }
  }
}

// ---------------------------------------------------------------------------
// Kernel 2 (r8-verified): pure streaming filter. Thresholds from meta[4/5]
// (cross-dispatch visibility by stream ordering). Plain cand stores (read by
// the NEXT dispatch). Bth<0 => append ALL masked (fallback signal).
// ---------------------------------------------------------------------------
__global__ void __launch_bounds__(256)
compact_kernel(const uint32_t* __restrict__ score, int M,
               int* __restrict__ meta,             // [0]=cnt_fg [1]=cnt_bg
               uint64_t* __restrict__ cand) {
  const int bth[2] = {meta[4], meta[5]};
  const int base = (blockIdx.x * 256 + threadIdx.x) * 4;
  if (base >= M) return;
  uint32_t ss[4];
  int lim;
  if (base + 3 < M) {
    uint4 s4 = *reinterpret_cast<const uint4*>(score + base);
    ss[0] = s4.x; ss[1] = s4.y; ss[2] = s4.z; ss[3] = s4.w;
    lim = 4;
  } else {
    lim = M - base;
    for (int k = 0; k < lim; ++k) ss[k] = score[base + k];
  }
  for (int k = 0; k < lim; ++k) {
    uint32_t s = ss[k];
    uint32_t mb = s & 3u;
    if (!mb) continue;
    int m = (mb & 2u) ? 0 : 1;
    int B = bth[m];
    if (B >= 0 && (int)(s >> 20) < B) continue;
    int p = atomicAdd(&meta[m], 1);
    if (p < CAND_MAX)
      cand[(size_t)m * CAND_MAX + p] =
          (((uint64_t)((s >> 9) + 1u)) << 32) | (uint64_t)(~(uint32_t)(base + k));
  }
}

// ---------------------------------------------------------------------------
// Kernel 3 (r8-verified): rank-based top-TK selection. Keys ((ubits+1)<<32)|~i
// are unique, so rank = #{keys > mine} reproduces the exact descending order
// == XLA stable top_k, independent of append order. Fused finalize.
// Output layout: rois[256*5] | labels[256] | targets[256*84]
// ---------------------------------------------------------------------------
__global__ void __launch_bounds__(1024)
final_kernel(const float* __restrict__ all_rois,
             const float* __restrict__ gt_boxes,
             const int* __restrict__ gt_labels,
             const uint32_t* __restrict__ score,
             const uint64_t* __restrict__ cand_g,
             const int* __restrict__ meta,
             float* __restrict__ out, int N, int M) {
  __shared__ uint64_t cand[CAND_MAX];
  __shared__ int keep[2 * TK];
  __shared__ int fgvalid[TK];
  __shared__ float s_tx[2 * TK], s_ty[2 * TK], s_tw[2 * TK], s_th[2 * TK];
  __shared__ int s_label[2 * TK];
  const int t = threadIdx.x;

  for (int m = 0; m < 2; ++m) {
    int cnt = meta[m]; if (cnt > CAND_MAX) cnt = CAND_MAX;
    for (int p = t; p < cnt; p += 1024)
      cand[p] = cand_g[(size_t)m * CAND_MAX + p];
    __syncthreads();
    for (int p = t; p < cnt; p += 1024) {
      uint64_t key = cand[p];
      int r = 0;
      for (int j = 0; j < cnt; ++j) r += (cand[j] > key) ? 1 : 0;
      if (r < TK) {
        keep[m * TK + r] = (int)(~(uint32_t)(key & 0xFFFFFFFFull));
        if (m == 0) fgvalid[r] = 1;
      }
    }
    __syncthreads();
    if (cnt < TK && t == 0) {         // mask had <TK members: pad with lowest-
      int fill = cnt;                 // index non-masked (JAX -1.0 tie semantics)
      uint32_t mask_bit = (m == 0) ? 2u : 1u;
      for (int i2 = 0; i2 < M && fill < TK; ++i2)
        if (!(score[i2] & mask_bit)) {
          keep[m * TK + fill] = i2;
          if (m == 0) fgvalid[fill] = 0;
          fill++;
        }
    }
    __syncthreads();
  }

  const int R = 2 * TK;
  float* rois_out   = out;
  float* labels_out = out + (size_t)R * 5;
  float* bt_out     = out + (size_t)R * 5 + R;

  if (t < R) {
    const int i = keep[t];
    float rimg, rx1, ry1, rx2, ry2;
    if (i < N) {
      rimg = all_rois[(size_t)i * 5 + 0];
      rx1  = all_rois[(size_t)i * 5 + 1];
      ry1  = all_rois[(size_t)i * 5 + 2];
      rx2  = all_rois[(size_t)i * 5 + 3];
      ry2  = all_rois[(size_t)i * 5 + 4];
    } else {
      int g = i - N;
      rimg = 0.0f;
      rx1 = gt_boxes[g * 4 + 0]; ry1 = gt_boxes[g * 4 + 1];
      rx2 = gt_boxes[g * 4 + 2]; ry2 = gt_boxes[g * 4 + 3];
    }
    rois_out[t * 5 + 0] = rimg;
    rois_out[t * 5 + 1] = rx1;
    rois_out[t * 5 + 2] = ry1;
    rois_out[t * 5 + 3] = rx2;
    rois_out[t * 5 + 4] = ry2;

    const int ga = (int)((score[i] >> 2) & 127u);
    int label = (t < TK && fgvalid[t]) ? gt_labels[ga] : 0;
    labels_out[t] = (float)label;
    s_label[t] = label;

    float gx1 = gt_boxes[ga * 4 + 0], gy1 = gt_boxes[ga * 4 + 1];
    float gx2 = gt_boxes[ga * 4 + 2], gy2 = gt_boxes[ga * 4 + 3];
    float ew = rx2 - rx1 + 1.0f, eh = ry2 - ry1 + 1.0f;
    float ecx = rx1 + 0.5f * ew, ecy = ry1 + 0.5f * eh;
    float gw = gx2 - gx1 + 1.0f, gh = gy2 - gy1 + 1.0f;
    float gcx = gx1 + 0.5f * gw, gcy = gy1 + 0.5f * gh;
    s_tx[t] = (gcx - ecx) / ew;
    s_ty[t] = (gcy - ecy) / eh;
    s_tw[t] = logf(gw / ew);
    s_th[t] = logf(gh / eh);
  }
  __syncthreads();

  const int TOT = R * 4 * NUM_CLASSES;
  for (int idx = t; idx < TOT; idx += 1024) {
    int r = idx / (4 * NUM_CLASSES);
    int c = idx - r * (4 * NUM_CLASSES);
    int lab = s_label[r];
    float v = 0.0f;
    if (lab > 0 && (c >> 2) == lab) {
      int cc = c & 3;
      v = (cc == 0) ? s_tx[r] : (cc == 1) ? s_ty[r] : (cc == 2) ? s_tw[r] : s_th[r];
    }
    bt_out[idx] = v;
  }
}

// ---------------------------------------------------------------------------
extern "C" void kernel_launch(void* const* d_in, const int* in_sizes, int n_in,
                              void* d_out, int out_size, void* d_ws, size_t ws_size,
                              hipStream_t stream) {
  const float* all_rois = (const float*)d_in[0];
  const float* gt_boxes = (const float*)d_in[1];
  const int*   gt_labels = (const int*)d_in[2];
  const int N = in_sizes[0] / 5;
  const int G = in_sizes[2];
  const int M = N + G;

  // workspace: [meta 256B][hist 32KB][score M*4][cand 64KB]
  char* ws = (char*)d_ws;
  int* meta = (int*)ws;                       // see score_kernel comment
  uint32_t* hist = (uint32_t*)(ws + 256);
  size_t off = 256 + (size_t)2 * NBINS * 4;
  uint32_t* score = (uint32_t*)(ws + off);
  off += (((size_t)M * 4) + 255) & ~(size_t)255;
  uint64_t* cand = (uint64_t*)(ws + off);
  float* out = (float*)d_out;

  hipMemsetAsync(ws, 0, 256 + (size_t)2 * NBINS * 4, stream);
  const int nblocks = (M + 255) / 256;        // 256 ROIs per 1024-thread block
  score_kernel<<<nblocks, 1024, 0, stream>>>(all_rois, gt_boxes, score,
                                             hist, meta, N, M, G);
  const int nb4 = ((M + 3) / 4 + 255) / 256;
  compact_kernel<<<nb4, 256, 0, stream>>>(score, M, meta, cand);
  final_kernel<<<1, 1024, 0, stream>>>(all_rois, gt_boxes, gt_labels, score,
                                       cand, meta, out, N, M);
}